// Round 5
// baseline (19604.318 us; speedup 1.0000x reference)
//
#include <hip/hip_runtime.h>
#include <hip/hip_bf16.h>

// LSTMModel_with_theta: B=64, T=2048, H=256, 2-layer LSTM -> mean_t -> MLP.
//
// Round 5: ONE fabric hop per step.
//  - r4 cost 3 serial MALL trips/step: flag-poll RTT + data RTT + producer
//    vmcnt-drain before flag. Now shared data is SELF-SYNCHRONIZING:
//    u32 = (tag=t+1)<<16 | h_bf16. Consumers poll tagged data directly
//    (relaxed agent bypass loads, retry); producers fire relaxed stores and
//    move on (no flag, no ack drain).
//  - L0: 2 WGs/group (512thr, 8 waves). Wave owns 16 units x ALL 4 gates
//    (32 weight frags = 128 VGPR) -> EW fully per-lane. Own half of h in LDS;
//    only partner 128-unit half crosses fabric (staged coop, 16B/thread).
//  - L1: 8 WGs/group (32 units each, K=512 in-register, 16 frags). h0(t) and
//    peer h1(t-1) staged cooperatively into LDS (A0/A1), gates gathered with
//    3 shfl_xor + cndmask (no LDS round-trip).
//  - Ring reuse safety: pairwise mutual-progress proof (D>=4); seqring D=16
//    with coarse L1->L0 back-pressure (prog counters every 4 steps).
//  - Barriers: raw s_barrier + explicit lgkmcnt(0) (+sched_barrier, rule #18)
//    so global stores are NEVER drained in-loop.

#define BB 64
#define TT 2048
#define HH 256
#define D0 16
#define D1 4

typedef short s16x8 __attribute__((ext_vector_type(8)));
typedef float f32x4 __attribute__((ext_vector_type(4)));

__device__ inline unsigned short f2bf(float f) {
  unsigned u = __float_as_uint(f);
  u += 0x7fff + ((u >> 16) & 1);          // RNE
  return (unsigned short)(u >> 16);
}
__device__ inline float sigm(float x) { return 1.f / (1.f + __expf(-x)); }
__device__ inline float tanh_f(float x) { return 1.f - 2.f / (__expf(2.f * x) + 1.f); }

__device__ inline unsigned long long ld64(const unsigned int* p) {
  return __hip_atomic_load((const unsigned long long*)p, __ATOMIC_RELAXED,
                           __HIP_MEMORY_SCOPE_AGENT);
}
__device__ inline void st32(unsigned int* p, unsigned int v) {
  __hip_atomic_store(p, v, __ATOMIC_RELAXED, __HIP_MEMORY_SCOPE_AGENT);
}
__device__ inline void st32i(int* p, int v) {
  __hip_atomic_store(p, v, __ATOMIC_RELAXED, __HIP_MEMORY_SCOPE_AGENT);
}
__device__ inline int ld32i(const int* p) {
  return __hip_atomic_load(p, __ATOMIC_RELAXED, __HIP_MEMORY_SCOPE_AGENT);
}
// barrier WITHOUT vmcnt drain: LDS-fence only (global tagged stores fly free)
__device__ inline void wg_bar() {
  asm volatile("s_waitcnt lgkmcnt(0)" ::: "memory");
  __builtin_amdgcn_sched_barrier(0);
  __builtin_amdgcn_s_barrier();
  __builtin_amdgcn_sched_barrier(0);
}

#define MFMA(a, b, c) __builtin_amdgcn_mfma_f32_16x16x32_bf16((a), (b), (c), 0, 0, 0)

__global__ void xt_kernel(const float* __restrict__ x, float* __restrict__ xT) {
  int i = blockIdx.x * 256 + threadIdx.x;   // 131072 total
  int b = i & 63, t = i >> 6;
  xT[(size_t)t * BB + b] = x[(size_t)b * TT + t];
}

__global__ __launch_bounds__(512, 2)
void lstm_kernel(const float* __restrict__ Wx0, const float* __restrict__ Wh0,
                 const float* __restrict__ b0v,
                 const float* __restrict__ Wx1, const float* __restrict__ Wh1,
                 const float* __restrict__ b1v,
                 const float* __restrict__ xT,
                 unsigned int* __restrict__ seqring,   // [4][D0][16][256] tagged u32
                 unsigned int* __restrict__ h1ring,    // [4][D1][16][256] tagged u32
                 float* __restrict__ hmean, int* prog)
{
  __shared__ __align__(16) char Ab [16 * 512];   // [row][unit 256] bf16, XOR-swizzled
  __shared__ __align__(16) char Ab1[16 * 512];   // L1 only: h1(t-1)

  const int tid  = threadIdx.x;
  const int lane = tid & 63;
  const int w    = tid >> 6;        // wave 0..7
  const int u16  = lane & 15;
  const int kgrp = lane >> 4;
  const int arow = lane & 15;
  const int bid  = blockIdx.x;

  if (bid < 8) {
    // ================= LAYER 0: 2 WGs/group, 128 units each, K=256 =================
    const int g = bid >> 1, ho = bid & 1, po = 1 - ho;
    const int U = ho * 128 + w * 16 + u16;       // lane's unit (owns all 4 gates)
    s16x8 bw[32];                                // [gate*8 + ks] : 128 VGPRs
#pragma unroll
    for (int n = 0; n < 4; ++n)
#pragma unroll
      for (int ks = 0; ks < 8; ++ks) {
        const int col = n * 256 + U;
#pragma unroll
        for (int j = 0; j < 8; ++j)
          bw[n * 8 + ks][j] = (short)f2bf(Wh0[(size_t)(ks * 32 + kgrp * 8 + j) * 1024 + col]);
      }
    float bE[4], xE[4];
#pragma unroll
    for (int n = 0; n < 4; ++n) { bE[n] = b0v[n * 256 + U]; xE[n] = Wx0[n * 256 + U]; }

    unsigned int* sr = seqring + (size_t)g * D0 * 4096;
    const int sidx = tid * 4, srow = sidx >> 7, spc = sidx & 127;  // stage: 4 u32/thread
    float cL[4] = {0.f, 0.f, 0.f, 0.f};

    for (int t = 0; t < TT; ++t) {
      if ((t & 7) == 0 && t >= 16 && tid < 8) {      // L1 back-pressure (coarse)
        const int need = t - 8;
        while (ld32i(&prog[g * 8 + tid]) < need) __builtin_amdgcn_s_sleep(8);
      }
      wg_bar();                                       // top: prev writes fenced
      float xr[4];
#pragma unroll
      for (int r = 0; r < 4; ++r) xr[r] = xT[(size_t)t * BB + g * 16 + kgrp * 4 + r];

      f32x4 acc[4] = {{0,0,0,0},{0,0,0,0},{0,0,0,0},{0,0,0,0}};
      if (t > 0) {
        // issue partner-half tagged loads (h(t-1)) -- the ONE fabric hop
        const unsigned int* sb = sr + ((t - 1) & (D0 - 1)) * 4096 + srow * 256 + po * 128 + spc;
        unsigned long long q0 = ld64(sb), q1 = ld64(sb + 2);
        // own-half frags from LDS + MFMA (overlaps the hop)
        s16x8 ao[4];
#pragma unroll
        for (int i = 0; i < 4; ++i) {
          const int ks = ho * 4 + i;
          ao[i] = *(const s16x8*)(Ab + ((arow * 512 + (ks * 32 + kgrp * 8) * 2) ^ ((arow & 7) << 4)));
        }
#pragma unroll
        for (int i = 0; i < 4; ++i) {
          const int f = ho * 4 + i;
#pragma unroll
          for (int n = 0; n < 4; ++n) acc[n] = MFMA(ao[i], bw[n * 8 + f], acc[n]);
        }
        // verify tags, retry (steady state: first check passes)
        const unsigned int tg = (unsigned int)t;
        for (;;) {
          const bool ok = (((q0 >> 16) & 0xFFFFu) == tg) & ((unsigned)(q0 >> 48) == tg) &
                          (((q1 >> 16) & 0xFFFFu) == tg) & ((unsigned)(q1 >> 48) == tg);
          if (__all(ok)) break;
          __builtin_amdgcn_s_sleep(1);
          q0 = ld64(sb); q1 = ld64(sb + 2);
        }
        const unsigned int lo = (unsigned)(q0 & 0xFFFF) | (((unsigned)(q0 >> 32) & 0xFFFF) << 16);
        const unsigned int hi = (unsigned)(q1 & 0xFFFF) | (((unsigned)(q1 >> 32) & 0xFFFF) << 16);
        *(uint2*)(Ab + ((srow * 512 + (po * 128 + spc) * 2) ^ ((srow & 7) << 4))) = (uint2){lo, hi};
      }
      wg_bar();                                       // staging complete
      if (t > 0) {
        s16x8 ap[4];
#pragma unroll
        for (int i = 0; i < 4; ++i) {
          const int ks = po * 4 + i;
          ap[i] = *(const s16x8*)(Ab + ((arow * 512 + (ks * 32 + kgrp * 8) * 2) ^ ((arow & 7) << 4)));
        }
#pragma unroll
        for (int i = 0; i < 4; ++i) {
          const int f = po * 4 + i;
#pragma unroll
          for (int n = 0; n < 4; ++n) acc[n] = MFMA(ap[i], bw[n * 8 + f], acc[n]);
        }
      }
      // EW fully per-lane (all 4 gates in acc[0..3]); publish tagged + LDS own h
      const unsigned int tagw = (unsigned)(t + 1) << 16;
#pragma unroll
      for (int r = 0; r < 4; ++r) {
        const int row = kgrp * 4 + r;
        const float gi = acc[0][r] + bE[0] + xr[r] * xE[0];
        const float gf = acc[1][r] + bE[1] + xr[r] * xE[1];
        const float gg = acc[2][r] + bE[2] + xr[r] * xE[2];
        const float go = acc[3][r] + bE[3] + xr[r] * xE[3];
        cL[r] = sigm(gf) * cL[r] + sigm(gi) * tanh_f(gg);
        const float hv = sigm(go) * tanh_f(cL[r]);
        const unsigned short hb = f2bf(hv);
        st32(sr + (t & (D0 - 1)) * 4096 + row * 256 + U, tagw | hb);
        *(unsigned short*)(Ab + ((row * 512 + U * 2) ^ ((row & 7) << 4))) = hb;
      }
    }
  } else {
    // ================= LAYER 1: 8 WGs/group, 32 units each, K=512 =================
    const int idx = bid - 8, g = idx >> 3, q = idx & 7;
    const int go_ = u16 >> 2;                    // lane's MFMA gate
    const int U   = q * 32 + w * 4 + (u16 & 3);  // lane's unit
    s16x8 bw[16];                                // [ks]: ks<8 Wx1, ks>=8 Wh1 : 64 VGPRs
#pragma unroll
    for (int ks = 0; ks < 16; ++ks) {
      const int col = go_ * 256 + U;
#pragma unroll
      for (int j = 0; j < 8; ++j) {
        const int k = (ks & 7) * 32 + kgrp * 8 + j;
        bw[ks][j] = (short)f2bf((ks < 8) ? Wx1[(size_t)k * 1024 + col]
                                         : Wh1[(size_t)k * 1024 + col]);
      }
    }
    float bE[4];
#pragma unroll
    for (int n = 0; n < 4; ++n) bE[n] = b1v[n * 256 + U];

    unsigned int* sr = seqring + (size_t)g * D0 * 4096;
    unsigned int* hr = h1ring  + (size_t)g * D1 * 4096;
    const int half = tid >> 8, st2 = tid & 255;
    const int srow = st2 >> 4, scol = (st2 & 15) * 16;   // stage: 16 u32/thread
    float cL[4] = {0.f, 0.f, 0.f, 0.f}, hs[4] = {0.f, 0.f, 0.f, 0.f};

    for (int t = 0; t < TT; ++t) {
      if ((t & 3) == 3 && tid == 0) st32i(&prog[g * 8 + q], t);   // progress (coarse)
      wg_bar();                                       // top
      // ---- cooperative tagged staging: A0 = h0(t), A1 = h1(t-1) ----
      if (half == 0) {
        const unsigned int* sb = sr + (t & (D0 - 1)) * 4096 + srow * 256 + scol;
        unsigned long long qv[8];
        const unsigned int tg = (unsigned int)(t + 1);
        for (;;) {
          bool ok = true;
#pragma unroll
          for (int i = 0; i < 8; ++i) {
            qv[i] = ld64(sb + i * 2);
            ok &= (((qv[i] >> 16) & 0xFFFFu) == tg) & ((unsigned)(qv[i] >> 48) == tg);
          }
          if (__all(ok)) break;
          __builtin_amdgcn_s_sleep(1);
        }
        unsigned int wv[8];
#pragma unroll
        for (int i = 0; i < 8; ++i)
          wv[i] = (unsigned)(qv[i] & 0xFFFF) | (((unsigned)(qv[i] >> 32) & 0xFFFF) << 16);
        const int ba = srow * 512 + scol * 2;
        *(uint4*)(Ab + ((ba     ) ^ ((srow & 7) << 4))) = (uint4){wv[0], wv[1], wv[2], wv[3]};
        *(uint4*)(Ab + ((ba + 16) ^ ((srow & 7) << 4))) = (uint4){wv[4], wv[5], wv[6], wv[7]};
      } else if (t > 0) {
        const unsigned int* sb = hr + ((t - 1) & (D1 - 1)) * 4096 + srow * 256 + scol;
        unsigned long long qv[8];
        const unsigned int tg = (unsigned int)t;
        for (;;) {
          bool ok = true;
#pragma unroll
          for (int i = 0; i < 8; ++i) {
            qv[i] = ld64(sb + i * 2);
            ok &= (((qv[i] >> 16) & 0xFFFFu) == tg) & ((unsigned)(qv[i] >> 48) == tg);
          }
          if (__all(ok)) break;
          __builtin_amdgcn_s_sleep(1);
        }
        unsigned int wv[8];
#pragma unroll
        for (int i = 0; i < 8; ++i)
          wv[i] = (unsigned)(qv[i] & 0xFFFF) | (((unsigned)(qv[i] >> 32) & 0xFFFF) << 16);
        const int ba = srow * 512 + scol * 2;
        *(uint4*)(Ab1 + ((ba     ) ^ ((srow & 7) << 4))) = (uint4){wv[0], wv[1], wv[2], wv[3]};
        *(uint4*)(Ab1 + ((ba + 16) ^ ((srow & 7) << 4))) = (uint4){wv[4], wv[5], wv[6], wv[7]};
      }
      wg_bar();                                       // staged
      f32x4 accA = {0,0,0,0}, accB = {0,0,0,0};
      {
        s16x8 a0[8];
#pragma unroll
        for (int ks = 0; ks < 8; ++ks)
          a0[ks] = *(const s16x8*)(Ab + ((arow * 512 + (ks * 32 + kgrp * 8) * 2) ^ ((arow & 7) << 4)));
#pragma unroll
        for (int ks = 0; ks < 8; ++ks) accA = MFMA(a0[ks], bw[ks], accA);
      }
      if (t > 0) {
        s16x8 a1[8];
#pragma unroll
        for (int ks = 0; ks < 8; ++ks)
          a1[ks] = *(const s16x8*)(Ab1 + ((arow * 512 + (ks * 32 + kgrp * 8) * 2) ^ ((arow & 7) << 4)));
#pragma unroll
        for (int ks = 0; ks < 8; ++ks) accB = MFMA(a1[ks], bw[8 + ks], accB);
      }
      // EW: gather 4 gates via shfl_xor(4,8,12) + cndmask
      const unsigned int tagw = (unsigned)(t + 1) << 16;
      const bool b0 = go_ & 1, b1 = go_ & 2;
#pragma unroll
      for (int r = 0; r < 4; ++r) {
        const float av = accA[r] + accB[r];
        const float Bv = __shfl_xor(av, 4);
        const float Cv = __shfl_xor(av, 8);
        const float Dv = __shfl_xor(av, 12);
        const float e0 = b0 ? Bv : av,  e1 = b0 ? av : Bv;
        const float f0 = b0 ? Dv : Cv,  f1 = b0 ? Cv : Dv;
        const float gi = (b1 ? f0 : e0) + bE[0];
        const float gf = (b1 ? f1 : e1) + bE[1];
        const float gg = (b1 ? e0 : f0) + bE[2];
        const float go = (b1 ? e1 : f1) + bE[3];
        cL[r] = sigm(gf) * cL[r] + sigm(gi) * tanh_f(gg);
        const float hv = sigm(go) * tanh_f(cL[r]);
        hs[r] += hv;
        if (u16 < 4)
          st32(hr + (t & (D1 - 1)) * 4096 + (kgrp * 4 + r) * 256 + U, tagw | f2bf(hv));
      }
    }
    if (u16 < 4) {
#pragma unroll
      for (int r = 0; r < 4; ++r)
        hmean[(size_t)(g * 16 + kgrp * 4 + r) * HH + U] = hs[r] * (1.f / TT);
    }
  }
}

__global__ __launch_bounds__(256)
void mlp_kernel(const float* __restrict__ theta, const float* __restrict__ Wtp,
                const float* __restrict__ btp, const float* __restrict__ Wl1,
                const float* __restrict__ bl1, const float* __restrict__ Wl2,
                const float* __restrict__ bl2, const float* __restrict__ Wo,
                const float* __restrict__ bo, const float* __restrict__ hmean,
                float* __restrict__ out)
{
  const int b = blockIdx.x;
  const int j = threadIdx.x;
  __shared__ float z[2 * HH];
  __shared__ float z1s[HH];
  __shared__ float red[256];

  float tp = btp[j];
#pragma unroll
  for (int d = 0; d < 5; ++d) tp += theta[b * 5 + d] * Wtp[d * HH + j];
  z[j] = hmean[(size_t)b * HH + j];
  z[HH + j] = tp;
  __syncthreads();

  float a1 = bl1[j];
  for (int k = 0; k < 2 * HH; ++k) a1 += z[k] * Wl1[(size_t)k * 256 + j];
  a1 = (a1 > 0.f) ? a1 : (__expf(a1) - 1.f);
  z1s[j] = a1;
  __syncthreads();

  float a2 = bl2[j];
  for (int k = 0; k < HH; ++k) a2 += z1s[k] * Wl2[(size_t)k * 256 + j];
  a2 = (a2 > 0.f) ? a2 : (__expf(a2) - 1.f);
  red[j] = a2 * Wo[j];
  __syncthreads();
  for (int s = 128; s > 0; s >>= 1) {
    if (j < s) red[j] += red[j + s];
    __syncthreads();
  }
  if (j == 0) out[b] = red[0] + bo[0];
}

extern "C" void kernel_launch(void* const* d_in, const int* in_sizes, int n_in,
                              void* d_out, int out_size, void* d_ws, size_t ws_size,
                              hipStream_t stream) {
  const float* x    = (const float*)d_in[0];
  const float* theta= (const float*)d_in[1];
  const float* Wx0  = (const float*)d_in[2];
  const float* Wh0  = (const float*)d_in[3];
  const float* b0   = (const float*)d_in[4];
  const float* Wx1  = (const float*)d_in[5];
  const float* Wh1  = (const float*)d_in[6];
  const float* b1   = (const float*)d_in[7];
  const float* Wtp  = (const float*)d_in[8];
  const float* btp  = (const float*)d_in[9];
  const float* Wl1  = (const float*)d_in[10];
  const float* bl1  = (const float*)d_in[11];
  const float* Wl2  = (const float*)d_in[12];
  const float* bl2  = (const float*)d_in[13];
  const float* Wo   = (const float*)d_in[14];
  const float* bo   = (const float*)d_in[15];

  // ws: prog 8KB (memset) | seqring u32 [4][16][16][256] 1MB | h1ring u32 [4][4][16][256] 256KB
  //     | hmean f32 64KB | xT f32 512KB   (tagged rings need no init: tags self-disambiguate)
  char* ws = (char*)d_ws;
  int* prog             = (int*)ws;
  unsigned int* seqring = (unsigned int*)(ws + 8192);
  unsigned int* h1ring  = (unsigned int*)(ws + 8192 + 1048576);
  float* hmean          = (float*)(ws + 8192 + 1048576 + 262144);
  float* xT             = (float*)(ws + 8192 + 1048576 + 262144 + 65536);
  const size_t WS_NEED = 8192ull + 1048576 + 262144 + 65536 + 524288;
  if (ws_size < WS_NEED) return;

  hipMemsetAsync(d_ws, 0, 8192, stream);

  xt_kernel<<<dim3((BB * TT) / 256), dim3(256), 0, stream>>>(x, xT);
  lstm_kernel<<<dim3(40), dim3(512), 0, stream>>>(
      Wx0, Wh0, b0, Wx1, Wh1, b1, xT, seqring, h1ring, hmean, prog);
  mlp_kernel<<<dim3(BB), dim3(256), 0, stream>>>(
      theta, Wtp, btp, Wl1, bl1, Wl2, bl2, Wo, bo, hmean, (float*)d_out);
}

// Round 6
// 19598.148 us; speedup vs baseline: 1.0003x; 1.0003x over previous
//
#include <hip/hip_runtime.h>
#include <hip/hip_bf16.h>

// LSTMModel_with_theta: B=64, T=2048, H=256, 2-layer LSTM -> mean_t -> MLP.
//
// Round 6: round-5 structure, ONE fix: __launch_bounds__(512, 1).
//  - r5 declared (512,2) => 4 waves/SIMD => 128-VGPR allocator cap; L0's 32
//    weight frags (128 VGPR) spilled to scratch (VGPR=108, WRITE_SIZE 3x,
//    19.6ms + 50ms outliers). (512,1) => 2 waves/SIMD => 256-VGPR cap; peak
//    live set ~190 fits. Only one WG/CU anyway (40 WGs on 256 CUs).
//  - Everything else identical to r5: self-synchronizing tagged u32 data
//    (tag=t+1)<<16 | h_bf16, relaxed agent atomics only (no acquire/release
//    cache maintenance), ONE fabric hop per step, barriers via s_barrier +
//    lgkmcnt only (global stores never drained in-loop).
//  - L0: 2 WGs/group (512thr), wave owns 16 units x all 4 gates (128 VGPR of
//    weights), own h-half in LDS, partner half staged coop from tagged ring.
//  - L1: 8 WGs/group, K=512 in-register (64 VGPR), h0(t)/h1(t-1) staged coop
//    into LDS, gate gather via 3 shfl_xor + cndmask.

#define BB 64
#define TT 2048
#define HH 256
#define D0 16
#define D1 4

typedef short s16x8 __attribute__((ext_vector_type(8)));
typedef float f32x4 __attribute__((ext_vector_type(4)));

__device__ inline unsigned short f2bf(float f) {
  unsigned u = __float_as_uint(f);
  u += 0x7fff + ((u >> 16) & 1);          // RNE
  return (unsigned short)(u >> 16);
}
__device__ inline float sigm(float x) { return 1.f / (1.f + __expf(-x)); }
__device__ inline float tanh_f(float x) { return 1.f - 2.f / (__expf(2.f * x) + 1.f); }

__device__ inline unsigned long long ld64(const unsigned int* p) {
  return __hip_atomic_load((const unsigned long long*)p, __ATOMIC_RELAXED,
                           __HIP_MEMORY_SCOPE_AGENT);
}
__device__ inline void st32(unsigned int* p, unsigned int v) {
  __hip_atomic_store(p, v, __ATOMIC_RELAXED, __HIP_MEMORY_SCOPE_AGENT);
}
__device__ inline void st32i(int* p, int v) {
  __hip_atomic_store(p, v, __ATOMIC_RELAXED, __HIP_MEMORY_SCOPE_AGENT);
}
__device__ inline int ld32i(const int* p) {
  return __hip_atomic_load(p, __ATOMIC_RELAXED, __HIP_MEMORY_SCOPE_AGENT);
}
// barrier WITHOUT vmcnt drain: LDS-fence only (global tagged stores fly free)
__device__ inline void wg_bar() {
  asm volatile("s_waitcnt lgkmcnt(0)" ::: "memory");
  __builtin_amdgcn_sched_barrier(0);
  __builtin_amdgcn_s_barrier();
  __builtin_amdgcn_sched_barrier(0);
}

#define MFMA(a, b, c) __builtin_amdgcn_mfma_f32_16x16x32_bf16((a), (b), (c), 0, 0, 0)

__global__ void xt_kernel(const float* __restrict__ x, float* __restrict__ xT) {
  int i = blockIdx.x * 256 + threadIdx.x;   // 131072 total
  int b = i & 63, t = i >> 6;
  xT[(size_t)t * BB + b] = x[(size_t)b * TT + t];
}

__global__ __launch_bounds__(512, 1)
void lstm_kernel(const float* __restrict__ Wx0, const float* __restrict__ Wh0,
                 const float* __restrict__ b0v,
                 const float* __restrict__ Wx1, const float* __restrict__ Wh1,
                 const float* __restrict__ b1v,
                 const float* __restrict__ xT,
                 unsigned int* __restrict__ seqring,   // [4][D0][16][256] tagged u32
                 unsigned int* __restrict__ h1ring,    // [4][D1][16][256] tagged u32
                 float* __restrict__ hmean, int* prog)
{
  __shared__ __align__(16) char Ab [16 * 512];   // [row][unit 256] bf16, XOR-swizzled
  __shared__ __align__(16) char Ab1[16 * 512];   // L1 only: h1(t-1)

  const int tid  = threadIdx.x;
  const int lane = tid & 63;
  const int w    = tid >> 6;        // wave 0..7
  const int u16  = lane & 15;
  const int kgrp = lane >> 4;
  const int arow = lane & 15;
  const int bid  = blockIdx.x;

  if (bid < 8) {
    // ================= LAYER 0: 2 WGs/group, 128 units each, K=256 =================
    const int g = bid >> 1, ho = bid & 1, po = 1 - ho;
    const int U = ho * 128 + w * 16 + u16;       // lane's unit (owns all 4 gates)
    s16x8 bw[32];                                // [gate*8 + ks] : 128 VGPRs
#pragma unroll
    for (int n = 0; n < 4; ++n)
#pragma unroll
      for (int ks = 0; ks < 8; ++ks) {
        const int col = n * 256 + U;
#pragma unroll
        for (int j = 0; j < 8; ++j)
          bw[n * 8 + ks][j] = (short)f2bf(Wh0[(size_t)(ks * 32 + kgrp * 8 + j) * 1024 + col]);
      }
    float bE[4], xE[4];
#pragma unroll
    for (int n = 0; n < 4; ++n) { bE[n] = b0v[n * 256 + U]; xE[n] = Wx0[n * 256 + U]; }

    unsigned int* sr = seqring + (size_t)g * D0 * 4096;
    const int sidx = tid * 4, srow = sidx >> 7, spc = sidx & 127;  // stage: 4 u32/thread
    float cL[4] = {0.f, 0.f, 0.f, 0.f};

    for (int t = 0; t < TT; ++t) {
      if ((t & 7) == 0 && t >= 16 && tid < 8) {      // L1 back-pressure (coarse)
        const int need = t - 8;
        while (ld32i(&prog[g * 8 + tid]) < need) __builtin_amdgcn_s_sleep(8);
      }
      wg_bar();                                       // top: prev writes fenced
      float xr[4];
#pragma unroll
      for (int r = 0; r < 4; ++r) xr[r] = xT[(size_t)t * BB + g * 16 + kgrp * 4 + r];

      f32x4 acc[4] = {{0,0,0,0},{0,0,0,0},{0,0,0,0},{0,0,0,0}};
      if (t > 0) {
        // issue partner-half tagged loads (h(t-1)) -- the ONE fabric hop
        const unsigned int* sb = sr + ((t - 1) & (D0 - 1)) * 4096 + srow * 256 + po * 128 + spc;
        unsigned long long q0 = ld64(sb), q1 = ld64(sb + 2);
        // own-half frags from LDS + MFMA (overlaps the hop)
        s16x8 ao[4];
#pragma unroll
        for (int i = 0; i < 4; ++i) {
          const int ks = ho * 4 + i;
          ao[i] = *(const s16x8*)(Ab + ((arow * 512 + (ks * 32 + kgrp * 8) * 2) ^ ((arow & 7) << 4)));
        }
#pragma unroll
        for (int i = 0; i < 4; ++i) {
          const int f = ho * 4 + i;
#pragma unroll
          for (int n = 0; n < 4; ++n) acc[n] = MFMA(ao[i], bw[n * 8 + f], acc[n]);
        }
        // verify tags, retry (steady state: first check passes)
        const unsigned int tg = (unsigned int)t;
        for (;;) {
          const bool ok = (((q0 >> 16) & 0xFFFFu) == tg) & ((unsigned)(q0 >> 48) == tg) &
                          (((q1 >> 16) & 0xFFFFu) == tg) & ((unsigned)(q1 >> 48) == tg);
          if (__all(ok)) break;
          __builtin_amdgcn_s_sleep(1);
          q0 = ld64(sb); q1 = ld64(sb + 2);
        }
        const unsigned int lo = (unsigned)(q0 & 0xFFFF) | (((unsigned)(q0 >> 32) & 0xFFFF) << 16);
        const unsigned int hi = (unsigned)(q1 & 0xFFFF) | (((unsigned)(q1 >> 32) & 0xFFFF) << 16);
        *(uint2*)(Ab + ((srow * 512 + (po * 128 + spc) * 2) ^ ((srow & 7) << 4))) = (uint2){lo, hi};
      }
      wg_bar();                                       // staging complete
      if (t > 0) {
        s16x8 ap[4];
#pragma unroll
        for (int i = 0; i < 4; ++i) {
          const int ks = po * 4 + i;
          ap[i] = *(const s16x8*)(Ab + ((arow * 512 + (ks * 32 + kgrp * 8) * 2) ^ ((arow & 7) << 4)));
        }
#pragma unroll
        for (int i = 0; i < 4; ++i) {
          const int f = po * 4 + i;
#pragma unroll
          for (int n = 0; n < 4; ++n) acc[n] = MFMA(ap[i], bw[n * 8 + f], acc[n]);
        }
      }
      // EW fully per-lane (all 4 gates in acc[0..3]); publish tagged + LDS own h
      const unsigned int tagw = (unsigned)(t + 1) << 16;
#pragma unroll
      for (int r = 0; r < 4; ++r) {
        const int row = kgrp * 4 + r;
        const float gi = acc[0][r] + bE[0] + xr[r] * xE[0];
        const float gf = acc[1][r] + bE[1] + xr[r] * xE[1];
        const float gg = acc[2][r] + bE[2] + xr[r] * xE[2];
        const float go = acc[3][r] + bE[3] + xr[r] * xE[3];
        cL[r] = sigm(gf) * cL[r] + sigm(gi) * tanh_f(gg);
        const float hv = sigm(go) * tanh_f(cL[r]);
        const unsigned short hb = f2bf(hv);
        st32(sr + (t & (D0 - 1)) * 4096 + row * 256 + U, tagw | hb);
        *(unsigned short*)(Ab + ((row * 512 + U * 2) ^ ((row & 7) << 4))) = hb;
      }
    }
  } else {
    // ================= LAYER 1: 8 WGs/group, 32 units each, K=512 =================
    const int idx = bid - 8, g = idx >> 3, q = idx & 7;
    const int go_ = u16 >> 2;                    // lane's MFMA gate
    const int U   = q * 32 + w * 4 + (u16 & 3);  // lane's unit
    s16x8 bw[16];                                // [ks]: ks<8 Wx1, ks>=8 Wh1 : 64 VGPRs
#pragma unroll
    for (int ks = 0; ks < 16; ++ks) {
      const int col = go_ * 256 + U;
#pragma unroll
      for (int j = 0; j < 8; ++j) {
        const int k = (ks & 7) * 32 + kgrp * 8 + j;
        bw[ks][j] = (short)f2bf((ks < 8) ? Wx1[(size_t)k * 1024 + col]
                                         : Wh1[(size_t)k * 1024 + col]);
      }
    }
    float bE[4];
#pragma unroll
    for (int n = 0; n < 4; ++n) bE[n] = b1v[n * 256 + U];

    unsigned int* sr = seqring + (size_t)g * D0 * 4096;
    unsigned int* hr = h1ring  + (size_t)g * D1 * 4096;
    const int half = tid >> 8, st2 = tid & 255;
    const int srow = st2 >> 4, scol = (st2 & 15) * 16;   // stage: 16 u32/thread
    float cL[4] = {0.f, 0.f, 0.f, 0.f}, hs[4] = {0.f, 0.f, 0.f, 0.f};

    for (int t = 0; t < TT; ++t) {
      if ((t & 3) == 3 && tid == 0) st32i(&prog[g * 8 + q], t);   // progress (coarse)
      wg_bar();                                       // top
      // ---- cooperative tagged staging: A0 = h0(t), A1 = h1(t-1) ----
      if (half == 0) {
        const unsigned int* sb = sr + (t & (D0 - 1)) * 4096 + srow * 256 + scol;
        unsigned long long qv[8];
        const unsigned int tg = (unsigned int)(t + 1);
        for (;;) {
          bool ok = true;
#pragma unroll
          for (int i = 0; i < 8; ++i) {
            qv[i] = ld64(sb + i * 2);
            ok &= (((qv[i] >> 16) & 0xFFFFu) == tg) & ((unsigned)(qv[i] >> 48) == tg);
          }
          if (__all(ok)) break;
          __builtin_amdgcn_s_sleep(1);
        }
        unsigned int wv[8];
#pragma unroll
        for (int i = 0; i < 8; ++i)
          wv[i] = (unsigned)(qv[i] & 0xFFFF) | (((unsigned)(qv[i] >> 32) & 0xFFFF) << 16);
        const int ba = srow * 512 + scol * 2;
        *(uint4*)(Ab + ((ba     ) ^ ((srow & 7) << 4))) = (uint4){wv[0], wv[1], wv[2], wv[3]};
        *(uint4*)(Ab + ((ba + 16) ^ ((srow & 7) << 4))) = (uint4){wv[4], wv[5], wv[6], wv[7]};
      } else if (t > 0) {
        const unsigned int* sb = hr + ((t - 1) & (D1 - 1)) * 4096 + srow * 256 + scol;
        unsigned long long qv[8];
        const unsigned int tg = (unsigned int)t;
        for (;;) {
          bool ok = true;
#pragma unroll
          for (int i = 0; i < 8; ++i) {
            qv[i] = ld64(sb + i * 2);
            ok &= (((qv[i] >> 16) & 0xFFFFu) == tg) & ((unsigned)(qv[i] >> 48) == tg);
          }
          if (__all(ok)) break;
          __builtin_amdgcn_s_sleep(1);
        }
        unsigned int wv[8];
#pragma unroll
        for (int i = 0; i < 8; ++i)
          wv[i] = (unsigned)(qv[i] & 0xFFFF) | (((unsigned)(qv[i] >> 32) & 0xFFFF) << 16);
        const int ba = srow * 512 + scol * 2;
        *(uint4*)(Ab1 + ((ba     ) ^ ((srow & 7) << 4))) = (uint4){wv[0], wv[1], wv[2], wv[3]};
        *(uint4*)(Ab1 + ((ba + 16) ^ ((srow & 7) << 4))) = (uint4){wv[4], wv[5], wv[6], wv[7]};
      }
      wg_bar();                                       // staged
      f32x4 accA = {0,0,0,0}, accB = {0,0,0,0};
      {
        s16x8 a0[8];
#pragma unroll
        for (int ks = 0; ks < 8; ++ks)
          a0[ks] = *(const s16x8*)(Ab + ((arow * 512 + (ks * 32 + kgrp * 8) * 2) ^ ((arow & 7) << 4)));
#pragma unroll
        for (int ks = 0; ks < 8; ++ks) accA = MFMA(a0[ks], bw[ks], accA);
      }
      if (t > 0) {
        s16x8 a1[8];
#pragma unroll
        for (int ks = 0; ks < 8; ++ks)
          a1[ks] = *(const s16x8*)(Ab1 + ((arow * 512 + (ks * 32 + kgrp * 8) * 2) ^ ((arow & 7) << 4)));
#pragma unroll
        for (int ks = 0; ks < 8; ++ks) accB = MFMA(a1[ks], bw[8 + ks], accB);
      }
      // EW: gather 4 gates via shfl_xor(4,8,12) + cndmask
      const unsigned int tagw = (unsigned)(t + 1) << 16;
      const bool b0 = go_ & 1, b1 = go_ & 2;
#pragma unroll
      for (int r = 0; r < 4; ++r) {
        const float av = accA[r] + accB[r];
        const float Bv = __shfl_xor(av, 4);
        const float Cv = __shfl_xor(av, 8);
        const float Dv = __shfl_xor(av, 12);
        const float e0 = b0 ? Bv : av,  e1 = b0 ? av : Bv;
        const float f0 = b0 ? Dv : Cv,  f1 = b0 ? Cv : Dv;
        const float gi = (b1 ? f0 : e0) + bE[0];
        const float gf = (b1 ? f1 : e1) + bE[1];
        const float gg = (b1 ? e0 : f0) + bE[2];
        const float go = (b1 ? e1 : f1) + bE[3];
        cL[r] = sigm(gf) * cL[r] + sigm(gi) * tanh_f(gg);
        const float hv = sigm(go) * tanh_f(cL[r]);
        hs[r] += hv;
        if (u16 < 4)
          st32(hr + (t & (D1 - 1)) * 4096 + (kgrp * 4 + r) * 256 + U, tagw | f2bf(hv));
      }
    }
    if (u16 < 4) {
#pragma unroll
      for (int r = 0; r < 4; ++r)
        hmean[(size_t)(g * 16 + kgrp * 4 + r) * HH + U] = hs[r] * (1.f / TT);
    }
  }
}

__global__ __launch_bounds__(256)
void mlp_kernel(const float* __restrict__ theta, const float* __restrict__ Wtp,
                const float* __restrict__ btp, const float* __restrict__ Wl1,
                const float* __restrict__ bl1, const float* __restrict__ Wl2,
                const float* __restrict__ bl2, const float* __restrict__ Wo,
                const float* __restrict__ bo, const float* __restrict__ hmean,
                float* __restrict__ out)
{
  const int b = blockIdx.x;
  const int j = threadIdx.x;
  __shared__ float z[2 * HH];
  __shared__ float z1s[HH];
  __shared__ float red[256];

  float tp = btp[j];
#pragma unroll
  for (int d = 0; d < 5; ++d) tp += theta[b * 5 + d] * Wtp[d * HH + j];
  z[j] = hmean[(size_t)b * HH + j];
  z[HH + j] = tp;
  __syncthreads();

  float a1 = bl1[j];
  for (int k = 0; k < 2 * HH; ++k) a1 += z[k] * Wl1[(size_t)k * 256 + j];
  a1 = (a1 > 0.f) ? a1 : (__expf(a1) - 1.f);
  z1s[j] = a1;
  __syncthreads();

  float a2 = bl2[j];
  for (int k = 0; k < HH; ++k) a2 += z1s[k] * Wl2[(size_t)k * 256 + j];
  a2 = (a2 > 0.f) ? a2 : (__expf(a2) - 1.f);
  red[j] = a2 * Wo[j];
  __syncthreads();
  for (int s = 128; s > 0; s >>= 1) {
    if (j < s) red[j] += red[j + s];
    __syncthreads();
  }
  if (j == 0) out[b] = red[0] + bo[0];
}

extern "C" void kernel_launch(void* const* d_in, const int* in_sizes, int n_in,
                              void* d_out, int out_size, void* d_ws, size_t ws_size,
                              hipStream_t stream) {
  const float* x    = (const float*)d_in[0];
  const float* theta= (const float*)d_in[1];
  const float* Wx0  = (const float*)d_in[2];
  const float* Wh0  = (const float*)d_in[3];
  const float* b0   = (const float*)d_in[4];
  const float* Wx1  = (const float*)d_in[5];
  const float* Wh1  = (const float*)d_in[6];
  const float* b1   = (const float*)d_in[7];
  const float* Wtp  = (const float*)d_in[8];
  const float* btp  = (const float*)d_in[9];
  const float* Wl1  = (const float*)d_in[10];
  const float* bl1  = (const float*)d_in[11];
  const float* Wl2  = (const float*)d_in[12];
  const float* bl2  = (const float*)d_in[13];
  const float* Wo   = (const float*)d_in[14];
  const float* bo   = (const float*)d_in[15];

  // ws: prog 8KB (memset) | seqring u32 [4][16][16][256] 1MB | h1ring u32 [4][4][16][256] 256KB
  //     | hmean f32 64KB | xT f32 512KB   (tagged rings need no init: tags self-disambiguate)
  char* ws = (char*)d_ws;
  int* prog             = (int*)ws;
  unsigned int* seqring = (unsigned int*)(ws + 8192);
  unsigned int* h1ring  = (unsigned int*)(ws + 8192 + 1048576);
  float* hmean          = (float*)(ws + 8192 + 1048576 + 262144);
  float* xT             = (float*)(ws + 8192 + 1048576 + 262144 + 65536);
  const size_t WS_NEED = 8192ull + 1048576 + 262144 + 65536 + 524288;
  if (ws_size < WS_NEED) return;

  hipMemsetAsync(d_ws, 0, 8192, stream);

  xt_kernel<<<dim3((BB * TT) / 256), dim3(256), 0, stream>>>(x, xT);
  lstm_kernel<<<dim3(40), dim3(512), 0, stream>>>(
      Wx0, Wh0, b0, Wx1, Wh1, b1, xT, seqring, h1ring, hmean, prog);
  mlp_kernel<<<dim3(BB), dim3(256), 0, stream>>>(
      theta, Wtp, btp, Wl1, bl1, Wl2, bl2, Wo, bo, hmean, (float*)d_out);
}

// Round 7
// 9758.339 us; speedup vs baseline: 2.0090x; 2.0083x over previous
//
#include <hip/hip_runtime.h>
#include <hip/hip_bf16.h>

// LSTMModel_with_theta: B=64, T=2048, H=256, 2-layer LSTM -> mean_t -> MLP.
//
// Round 7: r6 structure, ONE fix: compile-time weight-fragment indexing.
//  - r5/r6 L0 indexed bw[] with runtime ho/po (bw[n*8 + ho*4+i]) -> rule #20:
//    runtime-indexed ext_vector arrays are allocated in SCRATCH (VGPR=108,
//    WRITE_SIZE 3x = scratch writes, FETCH 1.2GB = scratch re-reads, 19.6ms).
//    launch_bounds was a red herring (r6 null result proved it).
//  - Now bw[] is laid out by PHASE: slots [n*8+0..3] = own-half K-steps,
//    [n*8+4..7] = partner-half. Runtime ho only appears in ADDRESSES (legal);
//    every register index is a literal after unroll.
//  - Everything else identical to r6: tagged self-sync u32 data, relaxed
//    agent atomics only, one fabric hop/step, s_barrier+lgkmcnt barriers.

#define BB 64
#define TT 2048
#define HH 256
#define D0 16
#define D1 4

typedef short s16x8 __attribute__((ext_vector_type(8)));
typedef float f32x4 __attribute__((ext_vector_type(4)));

__device__ inline unsigned short f2bf(float f) {
  unsigned u = __float_as_uint(f);
  u += 0x7fff + ((u >> 16) & 1);          // RNE
  return (unsigned short)(u >> 16);
}
__device__ inline float sigm(float x) { return 1.f / (1.f + __expf(-x)); }
__device__ inline float tanh_f(float x) { return 1.f - 2.f / (__expf(2.f * x) + 1.f); }

__device__ inline unsigned long long ld64(const unsigned int* p) {
  return __hip_atomic_load((const unsigned long long*)p, __ATOMIC_RELAXED,
                           __HIP_MEMORY_SCOPE_AGENT);
}
__device__ inline void st32(unsigned int* p, unsigned int v) {
  __hip_atomic_store(p, v, __ATOMIC_RELAXED, __HIP_MEMORY_SCOPE_AGENT);
}
__device__ inline void st32i(int* p, int v) {
  __hip_atomic_store(p, v, __ATOMIC_RELAXED, __HIP_MEMORY_SCOPE_AGENT);
}
__device__ inline int ld32i(const int* p) {
  return __hip_atomic_load(p, __ATOMIC_RELAXED, __HIP_MEMORY_SCOPE_AGENT);
}
// barrier WITHOUT vmcnt drain: LDS-fence only (global tagged stores fly free)
__device__ inline void wg_bar() {
  asm volatile("s_waitcnt lgkmcnt(0)" ::: "memory");
  __builtin_amdgcn_sched_barrier(0);
  __builtin_amdgcn_s_barrier();
  __builtin_amdgcn_sched_barrier(0);
}

#define MFMA(a, b, c) __builtin_amdgcn_mfma_f32_16x16x32_bf16((a), (b), (c), 0, 0, 0)

__global__ void xt_kernel(const float* __restrict__ x, float* __restrict__ xT) {
  int i = blockIdx.x * 256 + threadIdx.x;   // 131072 total
  int b = i & 63, t = i >> 6;
  xT[(size_t)t * BB + b] = x[(size_t)b * TT + t];
}

__global__ __launch_bounds__(512, 1)
void lstm_kernel(const float* __restrict__ Wx0, const float* __restrict__ Wh0,
                 const float* __restrict__ b0v,
                 const float* __restrict__ Wx1, const float* __restrict__ Wh1,
                 const float* __restrict__ b1v,
                 const float* __restrict__ xT,
                 unsigned int* __restrict__ seqring,   // [4][D0][16][256] tagged u32
                 unsigned int* __restrict__ h1ring,    // [4][D1][16][256] tagged u32
                 float* __restrict__ hmean, int* prog)
{
  __shared__ __align__(16) char Ab [16 * 512];   // [row][unit 256] bf16, XOR-swizzled
  __shared__ __align__(16) char Ab1[16 * 512];   // L1 only: h1(t-1)

  const int tid  = threadIdx.x;
  const int lane = tid & 63;
  const int w    = tid >> 6;        // wave 0..7
  const int u16  = lane & 15;
  const int kgrp = lane >> 4;
  const int arow = lane & 15;
  const int bid  = blockIdx.x;

  if (bid < 8) {
    // ================= LAYER 0: 2 WGs/group, 128 units each, K=256 =================
    const int g = bid >> 1, ho = bid & 1, po = 1 - ho;
    const int U = ho * 128 + w * 16 + u16;       // lane's unit (owns all 4 gates)
    // bw layout by PHASE (register indices all compile-time):
    //   bw[n*8 + 0..3] = own-half   K-steps (abs ks = ho*4+i)
    //   bw[n*8 + 4..7] = partner    K-steps (abs ks = po*4+i)
    s16x8 bw[32];                                // 128 VGPRs
#pragma unroll
    for (int n = 0; n < 4; ++n) {
#pragma unroll
      for (int ph = 0; ph < 2; ++ph) {
#pragma unroll
        for (int i = 0; i < 4; ++i) {
          const int ks = (ph == 0 ? ho : po) * 4 + i;    // runtime, address-only
          const int col = n * 256 + U;
#pragma unroll
          for (int j = 0; j < 8; ++j)
            bw[n * 8 + ph * 4 + i][j] =
                (short)f2bf(Wh0[(size_t)(ks * 32 + kgrp * 8 + j) * 1024 + col]);
        }
      }
    }
    float bE[4], xE[4];
#pragma unroll
    for (int n = 0; n < 4; ++n) { bE[n] = b0v[n * 256 + U]; xE[n] = Wx0[n * 256 + U]; }

    unsigned int* sr = seqring + (size_t)g * D0 * 4096;
    const int sidx = tid * 4, srow = sidx >> 7, spc = sidx & 127;  // stage: 4 u32/thread
    float cL[4] = {0.f, 0.f, 0.f, 0.f};

    for (int t = 0; t < TT; ++t) {
      if ((t & 7) == 0 && t >= 16 && tid < 8) {      // L1 back-pressure (coarse)
        const int need = t - 8;
        while (ld32i(&prog[g * 8 + tid]) < need) __builtin_amdgcn_s_sleep(8);
      }
      wg_bar();                                       // top: prev writes fenced
      float xr[4];
#pragma unroll
      for (int r = 0; r < 4; ++r) xr[r] = xT[(size_t)t * BB + g * 16 + kgrp * 4 + r];

      f32x4 acc[4] = {{0,0,0,0},{0,0,0,0},{0,0,0,0},{0,0,0,0}};
      if (t > 0) {
        // issue partner-half tagged loads (h(t-1)) -- the ONE fabric hop
        const unsigned int* sb = sr + ((t - 1) & (D0 - 1)) * 4096 + srow * 256 + po * 128 + spc;
        unsigned long long q0 = ld64(sb), q1 = ld64(sb + 2);
        // own-half frags from LDS + MFMA (overlaps the hop)
        s16x8 ao[4];
#pragma unroll
        for (int i = 0; i < 4; ++i) {
          const int ks = ho * 4 + i;                    // address-only
          ao[i] = *(const s16x8*)(Ab + ((arow * 512 + (ks * 32 + kgrp * 8) * 2) ^ ((arow & 7) << 4)));
        }
#pragma unroll
        for (int i = 0; i < 4; ++i) {
#pragma unroll
          for (int n = 0; n < 4; ++n) acc[n] = MFMA(ao[i], bw[n * 8 + i], acc[n]);  // static idx
        }
        // verify tags, retry (steady state: first check passes)
        const unsigned int tg = (unsigned int)t;
        for (;;) {
          const bool ok = (((q0 >> 16) & 0xFFFFu) == tg) & ((unsigned)(q0 >> 48) == tg) &
                          (((q1 >> 16) & 0xFFFFu) == tg) & ((unsigned)(q1 >> 48) == tg);
          if (__all(ok)) break;
          __builtin_amdgcn_s_sleep(1);
          q0 = ld64(sb); q1 = ld64(sb + 2);
        }
        const unsigned int lo = (unsigned)(q0 & 0xFFFF) | (((unsigned)(q0 >> 32) & 0xFFFF) << 16);
        const unsigned int hi = (unsigned)(q1 & 0xFFFF) | (((unsigned)(q1 >> 32) & 0xFFFF) << 16);
        *(uint2*)(Ab + ((srow * 512 + (po * 128 + spc) * 2) ^ ((srow & 7) << 4))) = (uint2){lo, hi};
      }
      wg_bar();                                       // staging complete
      if (t > 0) {
        s16x8 ap[4];
#pragma unroll
        for (int i = 0; i < 4; ++i) {
          const int ks = po * 4 + i;                    // address-only
          ap[i] = *(const s16x8*)(Ab + ((arow * 512 + (ks * 32 + kgrp * 8) * 2) ^ ((arow & 7) << 4)));
        }
#pragma unroll
        for (int i = 0; i < 4; ++i) {
#pragma unroll
          for (int n = 0; n < 4; ++n) acc[n] = MFMA(ap[i], bw[n * 8 + 4 + i], acc[n]);  // static idx
        }
      }
      // EW fully per-lane (all 4 gates in acc[0..3]); publish tagged + LDS own h
      const unsigned int tagw = (unsigned)(t + 1) << 16;
#pragma unroll
      for (int r = 0; r < 4; ++r) {
        const int row = kgrp * 4 + r;
        const float gi = acc[0][r] + bE[0] + xr[r] * xE[0];
        const float gf = acc[1][r] + bE[1] + xr[r] * xE[1];
        const float gg = acc[2][r] + bE[2] + xr[r] * xE[2];
        const float go = acc[3][r] + bE[3] + xr[r] * xE[3];
        cL[r] = sigm(gf) * cL[r] + sigm(gi) * tanh_f(gg);
        const float hv = sigm(go) * tanh_f(cL[r]);
        const unsigned short hb = f2bf(hv);
        st32(sr + (t & (D0 - 1)) * 4096 + row * 256 + U, tagw | hb);
        *(unsigned short*)(Ab + ((row * 512 + U * 2) ^ ((row & 7) << 4))) = hb;
      }
    }
  } else {
    // ================= LAYER 1: 8 WGs/group, 32 units each, K=512 =================
    const int idx = bid - 8, g = idx >> 3, q = idx & 7;
    const int go_ = u16 >> 2;                    // lane's MFMA gate
    const int U   = q * 32 + w * 4 + (u16 & 3);  // lane's unit
    s16x8 bw[16];                                // [ks]: ks<8 Wx1, ks>=8 Wh1 : 64 VGPRs
#pragma unroll
    for (int ks = 0; ks < 16; ++ks) {
      const int col = go_ * 256 + U;
#pragma unroll
      for (int j = 0; j < 8; ++j) {
        const int k = (ks & 7) * 32 + kgrp * 8 + j;
        bw[ks][j] = (short)f2bf((ks < 8) ? Wx1[(size_t)k * 1024 + col]
                                         : Wh1[(size_t)k * 1024 + col]);
      }
    }
    float bE[4];
#pragma unroll
    for (int n = 0; n < 4; ++n) bE[n] = b1v[n * 256 + U];

    unsigned int* sr = seqring + (size_t)g * D0 * 4096;
    unsigned int* hr = h1ring  + (size_t)g * D1 * 4096;
    const int half = tid >> 8, st2 = tid & 255;
    const int srow = st2 >> 4, scol = (st2 & 15) * 16;   // stage: 16 u32/thread
    float cL[4] = {0.f, 0.f, 0.f, 0.f}, hs[4] = {0.f, 0.f, 0.f, 0.f};

    for (int t = 0; t < TT; ++t) {
      if ((t & 3) == 3 && tid == 0) st32i(&prog[g * 8 + q], t);   // progress (coarse)
      wg_bar();                                       // top
      // ---- cooperative tagged staging: A0 = h0(t), A1 = h1(t-1) ----
      if (half == 0) {
        const unsigned int* sb = sr + (t & (D0 - 1)) * 4096 + srow * 256 + scol;
        unsigned long long qv[8];
        const unsigned int tg = (unsigned int)(t + 1);
        for (;;) {
          bool ok = true;
#pragma unroll
          for (int i = 0; i < 8; ++i) {
            qv[i] = ld64(sb + i * 2);
            ok &= (((qv[i] >> 16) & 0xFFFFu) == tg) & ((unsigned)(qv[i] >> 48) == tg);
          }
          if (__all(ok)) break;
          __builtin_amdgcn_s_sleep(1);
        }
        unsigned int wv[8];
#pragma unroll
        for (int i = 0; i < 8; ++i)
          wv[i] = (unsigned)(qv[i] & 0xFFFF) | (((unsigned)(qv[i] >> 32) & 0xFFFF) << 16);
        const int ba = srow * 512 + scol * 2;
        *(uint4*)(Ab + ((ba     ) ^ ((srow & 7) << 4))) = (uint4){wv[0], wv[1], wv[2], wv[3]};
        *(uint4*)(Ab + ((ba + 16) ^ ((srow & 7) << 4))) = (uint4){wv[4], wv[5], wv[6], wv[7]};
      } else if (t > 0) {
        const unsigned int* sb = hr + ((t - 1) & (D1 - 1)) * 4096 + srow * 256 + scol;
        unsigned long long qv[8];
        const unsigned int tg = (unsigned int)t;
        for (;;) {
          bool ok = true;
#pragma unroll
          for (int i = 0; i < 8; ++i) {
            qv[i] = ld64(sb + i * 2);
            ok &= (((qv[i] >> 16) & 0xFFFFu) == tg) & ((unsigned)(qv[i] >> 48) == tg);
          }
          if (__all(ok)) break;
          __builtin_amdgcn_s_sleep(1);
        }
        unsigned int wv[8];
#pragma unroll
        for (int i = 0; i < 8; ++i)
          wv[i] = (unsigned)(qv[i] & 0xFFFF) | (((unsigned)(qv[i] >> 32) & 0xFFFF) << 16);
        const int ba = srow * 512 + scol * 2;
        *(uint4*)(Ab1 + ((ba     ) ^ ((srow & 7) << 4))) = (uint4){wv[0], wv[1], wv[2], wv[3]};
        *(uint4*)(Ab1 + ((ba + 16) ^ ((srow & 7) << 4))) = (uint4){wv[4], wv[5], wv[6], wv[7]};
      }
      wg_bar();                                       // staged
      f32x4 accA = {0,0,0,0}, accB = {0,0,0,0};
      {
        s16x8 a0[8];
#pragma unroll
        for (int ks = 0; ks < 8; ++ks)
          a0[ks] = *(const s16x8*)(Ab + ((arow * 512 + (ks * 32 + kgrp * 8) * 2) ^ ((arow & 7) << 4)));
#pragma unroll
        for (int ks = 0; ks < 8; ++ks) accA = MFMA(a0[ks], bw[ks], accA);
      }
      if (t > 0) {
        s16x8 a1[8];
#pragma unroll
        for (int ks = 0; ks < 8; ++ks)
          a1[ks] = *(const s16x8*)(Ab1 + ((arow * 512 + (ks * 32 + kgrp * 8) * 2) ^ ((arow & 7) << 4)));
#pragma unroll
        for (int ks = 0; ks < 8; ++ks) accB = MFMA(a1[ks], bw[8 + ks], accB);
      }
      // EW: gather 4 gates via shfl_xor(4,8,12) + cndmask
      const unsigned int tagw = (unsigned)(t + 1) << 16;
      const bool b0 = go_ & 1, b1 = go_ & 2;
#pragma unroll
      for (int r = 0; r < 4; ++r) {
        const float av = accA[r] + accB[r];
        const float Bv = __shfl_xor(av, 4);
        const float Cv = __shfl_xor(av, 8);
        const float Dv = __shfl_xor(av, 12);
        const float e0 = b0 ? Bv : av,  e1 = b0 ? av : Bv;
        const float f0 = b0 ? Dv : Cv,  f1 = b0 ? Cv : Dv;
        const float gi = (b1 ? f0 : e0) + bE[0];
        const float gf = (b1 ? f1 : e1) + bE[1];
        const float gg = (b1 ? e0 : f0) + bE[2];
        const float go = (b1 ? e1 : f1) + bE[3];
        cL[r] = sigm(gf) * cL[r] + sigm(gi) * tanh_f(gg);
        const float hv = sigm(go) * tanh_f(cL[r]);
        hs[r] += hv;
        if (u16 < 4)
          st32(hr + (t & (D1 - 1)) * 4096 + (kgrp * 4 + r) * 256 + U, tagw | f2bf(hv));
      }
    }
    if (u16 < 4) {
#pragma unroll
      for (int r = 0; r < 4; ++r)
        hmean[(size_t)(g * 16 + kgrp * 4 + r) * HH + U] = hs[r] * (1.f / TT);
    }
  }
}

__global__ __launch_bounds__(256)
void mlp_kernel(const float* __restrict__ theta, const float* __restrict__ Wtp,
                const float* __restrict__ btp, const float* __restrict__ Wl1,
                const float* __restrict__ bl1, const float* __restrict__ Wl2,
                const float* __restrict__ bl2, const float* __restrict__ Wo,
                const float* __restrict__ bo, const float* __restrict__ hmean,
                float* __restrict__ out)
{
  const int b = blockIdx.x;
  const int j = threadIdx.x;
  __shared__ float z[2 * HH];
  __shared__ float z1s[HH];
  __shared__ float red[256];

  float tp = btp[j];
#pragma unroll
  for (int d = 0; d < 5; ++d) tp += theta[b * 5 + d] * Wtp[d * HH + j];
  z[j] = hmean[(size_t)b * HH + j];
  z[HH + j] = tp;
  __syncthreads();

  float a1 = bl1[j];
  for (int k = 0; k < 2 * HH; ++k) a1 += z[k] * Wl1[(size_t)k * 256 + j];
  a1 = (a1 > 0.f) ? a1 : (__expf(a1) - 1.f);
  z1s[j] = a1;
  __syncthreads();

  float a2 = bl2[j];
  for (int k = 0; k < HH; ++k) a2 += z1s[k] * Wl2[(size_t)k * 256 + j];
  a2 = (a2 > 0.f) ? a2 : (__expf(a2) - 1.f);
  red[j] = a2 * Wo[j];
  __syncthreads();
  for (int s = 128; s > 0; s >>= 1) {
    if (j < s) red[j] += red[j + s];
    __syncthreads();
  }
  if (j == 0) out[b] = red[0] + bo[0];
}

extern "C" void kernel_launch(void* const* d_in, const int* in_sizes, int n_in,
                              void* d_out, int out_size, void* d_ws, size_t ws_size,
                              hipStream_t stream) {
  const float* x    = (const float*)d_in[0];
  const float* theta= (const float*)d_in[1];
  const float* Wx0  = (const float*)d_in[2];
  const float* Wh0  = (const float*)d_in[3];
  const float* b0   = (const float*)d_in[4];
  const float* Wx1  = (const float*)d_in[5];
  const float* Wh1  = (const float*)d_in[6];
  const float* b1   = (const float*)d_in[7];
  const float* Wtp  = (const float*)d_in[8];
  const float* btp  = (const float*)d_in[9];
  const float* Wl1  = (const float*)d_in[10];
  const float* bl1  = (const float*)d_in[11];
  const float* Wl2  = (const float*)d_in[12];
  const float* bl2  = (const float*)d_in[13];
  const float* Wo   = (const float*)d_in[14];
  const float* bo   = (const float*)d_in[15];

  // ws: prog 8KB (memset) | seqring u32 [4][16][16][256] 1MB | h1ring u32 [4][4][16][256] 256KB
  //     | hmean f32 64KB | xT f32 512KB   (tagged rings need no init: tags self-disambiguate)
  char* ws = (char*)d_ws;
  int* prog             = (int*)ws;
  unsigned int* seqring = (unsigned int*)(ws + 8192);
  unsigned int* h1ring  = (unsigned int*)(ws + 8192 + 1048576);
  float* hmean          = (float*)(ws + 8192 + 1048576 + 262144);
  float* xT             = (float*)(ws + 8192 + 1048576 + 262144 + 65536);
  const size_t WS_NEED = 8192ull + 1048576 + 262144 + 65536 + 524288;
  if (ws_size < WS_NEED) return;

  hipMemsetAsync(d_ws, 0, 8192, stream);

  xt_kernel<<<dim3((BB * TT) / 256), dim3(256), 0, stream>>>(x, xT);
  lstm_kernel<<<dim3(40), dim3(512), 0, stream>>>(
      Wx0, Wh0, b0, Wx1, Wh1, b1, xT, seqring, h1ring, hmean, prog);
  mlp_kernel<<<dim3(BB), dim3(256), 0, stream>>>(
      theta, Wtp, btp, Wl1, bl1, Wl2, bl2, Wo, bo, hmean, (float*)d_out);
}